// Round 1
// baseline (1242.976 us; speedup 1.0000x reference)
//
#include <hip/hip_runtime.h>
#include <math.h>

// Problem constants (match reference)
#define BATCH 128
#define S 50
#define D 128
#define SAMPLE 12
#define NL 8            // l-rows per block in global agg kernel

__device__ __forceinline__ float leakyf(float x) { return x >= 0.f ? x : 0.2f * x; }
__device__ __forceinline__ float4 ld4(const float* p) { return *reinterpret_cast<const float4*>(p); }

// ---------------------------------------------------------------------------
// h = embedding[inputs];  h_local = softmax(masked leaky(h_i.h_j.a_k)) @ h
// One block per batch element. Writes h_local into d_out.
// ---------------------------------------------------------------------------
__global__ __launch_bounds__(256) void local_agg_kernel(
    const int* __restrict__ inputs, const int* __restrict__ adj,
    const float* __restrict__ emb, const float* __restrict__ a_local,
    float* __restrict__ out)
{
    __shared__ float h[S][D];        // 25.6 KB
    __shared__ float al[4][D];       // 2 KB
    __shared__ float alpha[S][S];    // 10 KB
    const int b = blockIdx.x;
    const int t = threadIdx.x;

    for (int idx = t; idx < S * D; idx += 256) {
        int i = idx / D, d = idx % D;
        h[i][d] = emb[inputs[b * S + i] * D + d];
    }
    for (int idx = t; idx < 4 * D; idx += 256) al[idx / D][idx % D] = a_local[idx];
    __syncthreads();

    for (int p = t; p < S * S; p += 256) {
        int i = p / S, j = p % S;
        int a = adj[b * S * S + p];
        float v = -9e15f;
        if (a >= 1 && a <= 4) {
            const float* ak = al[a - 1];
            float dot = 0.f;
            #pragma unroll 4
            for (int d = 0; d < D; ++d) dot += h[i][d] * h[j][d] * ak[d];
            v = leakyf(dot);
        }
        alpha[i][j] = v;
    }
    __syncthreads();

    if (t < S) {
        float m = -INFINITY;
        for (int j = 0; j < S; ++j) m = fmaxf(m, alpha[t][j]);
        float ssum = 0.f;
        for (int j = 0; j < S; ++j) { float e = expf(alpha[t][j] - m); alpha[t][j] = e; ssum += e; }
        float inv = 1.f / ssum;
        for (int j = 0; j < S; ++j) alpha[t][j] *= inv;
    }
    __syncthreads();

    for (int idx = t; idx < S * D; idx += 256) {
        int i = idx / D, d = idx % D;
        float acc = 0.f;
        #pragma unroll 5
        for (int j = 0; j < S; ++j) acc += alpha[i][j] * h[j][d];
        out[b * S * D + idx] = acc;
    }
}

// ---------------------------------------------------------------------------
// session[b,:] = sum_s emb[item[b,s]]*mask / sum_s mask
// ---------------------------------------------------------------------------
__global__ __launch_bounds__(128) void session_kernel(
    const int* __restrict__ item, const int* __restrict__ mask,
    const float* __restrict__ emb, float* __restrict__ session)
{
    const int b = blockIdx.x, d = threadIdx.x;
    float num = 0.f, den = 0.f;
    for (int s = 0; s < S; ++s) {
        float m = (float)mask[b * S + s];
        num += m * emb[item[b * S + s] * D + d];
        den += m;
    }
    session[b * D + d] = num / den;
}

// ---------------------------------------------------------------------------
// n1[b, i*12+s] = adj_all[inputs[b,i], s]
// ---------------------------------------------------------------------------
__global__ __launch_bounds__(256) void n1_kernel(
    const int* __restrict__ inputs, const int* __restrict__ adj_all,
    int* __restrict__ n1)
{
    int idx = blockIdx.x * 256 + threadIdx.x;
    if (idx >= BATCH * 600) return;
    int b = idx / 600, j = idx % 600;
    int node = inputs[b * S + j / SAMPLE];
    n1[idx] = adj_all[node * SAMPLE + j % SAMPLE];
}

// ---------------------------------------------------------------------------
// Fused _global_agg. One block = one b and NL=8 consecutive l rows (96 samples).
// MODE 0: n_hop=0,hop=0 (self=E[inputs], neigh=E[n1])            -> out0
// MODE 1: n_hop=0,hop=1 (self=E[n1],     neigh=E[adj_all[n1]])   -> out1
// MODE 2: n_hop=1,hop=0 (self=out0,      neigh=out1) + h_local   -> d_out
// ---------------------------------------------------------------------------
template <int MODE>
__global__ __launch_bounds__(256) void global_kernel(
    const int* __restrict__ inputs, const int* __restrict__ adj_all,
    const float* __restrict__ num_weight, const float* __restrict__ emb,
    const int* __restrict__ n1, const float* __restrict__ session,
    const float* __restrict__ ent_self, const float* __restrict__ ent_neigh,
    const float* __restrict__ W1, const float* __restrict__ W2,
    const float* __restrict__ W3, float* __restrict__ out, int L)
{
    __shared__ float nv[NL * SAMPLE][D];   // 49.2 KB gathered neighbor rows
    __shared__ float selfv[NL][D];         // 4 KB
    __shared__ float sess[D];
    __shared__ float nwgt[NL * SAMPLE];
    __shared__ float score[NL * SAMPLE];
    __shared__ float neigh[NL][D];
    __shared__ int   selfNode[NL];
    __shared__ int   neighIdx[NL * SAMPLE];

    const int b = blockIdx.y;
    const int l0 = blockIdx.x * NL;
    const int t = threadIdx.x;

    if (t < D) sess[t] = session[b * D + t];
    if (t < NL) {
        int l = l0 + t;
        int node = 0;
        if (l < L) node = (MODE == 1) ? n1[b * 600 + l] : inputs[b * S + l];
        selfNode[t] = node;
    }
    __syncthreads();

    if (t < NL * SAMPLE) {
        int li = t / SAMPLE, s = t % SAMPLE;
        int l = l0 + li;
        bool valid = (l < L);
        int row = -1;
        if (valid) {
            if (MODE == 0)      row = n1[b * 600 + l * SAMPLE + s];
            else if (MODE == 1) row = adj_all[selfNode[li] * SAMPLE + s];
            else                row = b * 600 + l * SAMPLE + s;   // into out1
        }
        neighIdx[t] = row;
        nwgt[t] = valid ? num_weight[selfNode[li] * SAMPLE + s] : 0.f;
    }
    __syncthreads();

    // gather neighbor rows (float4 coalesced per row)
    {
        const float4* nsrc4 = reinterpret_cast<const float4*>(MODE == 2 ? ent_neigh : emb);
        for (int q = t; q < NL * SAMPLE * (D / 4); q += 256) {
            int m = q >> 5, dq = q & 31;
            int row = neighIdx[m];
            float4 v = make_float4(0.f, 0.f, 0.f, 0.f);
            if (row >= 0) v = nsrc4[row * 32 + dq];
            reinterpret_cast<float4*>(nv[m])[dq] = v;
        }
        // self rows: exactly 256 float4s
        {
            int li = t >> 5, dq = t & 31;
            int l = l0 + li;
            float4 v = make_float4(0.f, 0.f, 0.f, 0.f);
            if (l < L) {
                if (MODE == 2) v = reinterpret_cast<const float4*>(ent_self)[(b * 50 + l) * 32 + dq];
                else           v = reinterpret_cast<const float4*>(emb)[selfNode[li] * 32 + dq];
            }
            reinterpret_cast<float4*>(selfv[li])[dq] = v;
        }
    }
    __syncthreads();

    // Phase 2: z[m,d'] = sum_d (sess[d]*nv[m][d])*W1[d][d'] + nw[m]*W1[128][d']
    //          score[m] = sum_d' leaky(z)*W2[d']
    // thread: tn = t&31 -> d' quad, tm = t>>5 -> 12 m rows
    {
        const int tn = t & 31;
        const int m0 = (t >> 5) * 12;
        float4 acc[12];
        #pragma unroll
        for (int i = 0; i < 12; ++i) acc[i] = make_float4(0.f, 0.f, 0.f, 0.f);

        #pragma unroll 2
        for (int d = 0; d < D; ++d) {
            float4 w = ld4(W1 + d * D + tn * 4);
            float sv = sess[d];
            #pragma unroll
            for (int i = 0; i < 12; ++i) {
                float f = nv[m0 + i][d] * sv;
                acc[i].x += f * w.x; acc[i].y += f * w.y;
                acc[i].z += f * w.z; acc[i].w += f * w.w;
            }
        }
        {   // feat[...,128] = neigh_w
            float4 w = ld4(W1 + D * D + tn * 4);
            #pragma unroll
            for (int i = 0; i < 12; ++i) {
                float f = nwgt[m0 + i];
                acc[i].x += f * w.x; acc[i].y += f * w.y;
                acc[i].z += f * w.z; acc[i].w += f * w.w;
            }
        }
        float4 w2 = ld4(W2 + tn * 4);
        #pragma unroll
        for (int i = 0; i < 12; ++i) {
            float p = leakyf(acc[i].x) * w2.x + leakyf(acc[i].y) * w2.y +
                      leakyf(acc[i].z) * w2.z + leakyf(acc[i].w) * w2.w;
            #pragma unroll
            for (int off = 16; off >= 1; off >>= 1) p += __shfl_xor(p, off);
            if (tn == 0) score[m0 + i] = p;
        }
    }
    __syncthreads();

    // Phase 3: softmax over 12 samples per l
    if (t < NL) {
        float mx = -INFINITY;
        #pragma unroll
        for (int s = 0; s < SAMPLE; ++s) mx = fmaxf(mx, score[t * SAMPLE + s]);
        float e[SAMPLE], ssum = 0.f;
        #pragma unroll
        for (int s = 0; s < SAMPLE; ++s) { e[s] = expf(score[t * SAMPLE + s] - mx); ssum += e[s]; }
        float inv = 1.f / ssum;
        #pragma unroll
        for (int s = 0; s < SAMPLE; ++s) score[t * SAMPLE + s] = e[s] * inv;
    }
    __syncthreads();

    // Phase 4: neigh[l][d] = sum_s alpha * nv
    for (int q = t; q < NL * D; q += 256) {
        int l = q / D, d = q % D;
        float a = 0.f;
        #pragma unroll
        for (int s = 0; s < SAMPLE; ++s) a += score[l * SAMPLE + s] * nv[l * SAMPLE + s][d];
        neigh[l][d] = a;
    }
    __syncthreads();

    // Phase 5: out[l][d'] = relu(self @ W3[:128] + neigh @ W3[128:])
    {
        const int l = t >> 5;
        const int tn = t & 31;
        float ox = 0.f, oy = 0.f, oz = 0.f, ow = 0.f;
        #pragma unroll 2
        for (int d = 0; d < D; ++d) {
            float4 w = ld4(W3 + d * D + tn * 4);
            float f = selfv[l][d];
            ox += f * w.x; oy += f * w.y; oz += f * w.z; ow += f * w.w;
        }
        #pragma unroll 2
        for (int d = 0; d < D; ++d) {
            float4 w = ld4(W3 + (D + d) * D + tn * 4);
            float f = neigh[l][d];
            ox += f * w.x; oy += f * w.y; oz += f * w.z; ow += f * w.w;
        }
        int l_glob = l0 + l;
        if (l_glob < L) {
            float4 r = make_float4(fmaxf(ox, 0.f), fmaxf(oy, 0.f), fmaxf(oz, 0.f), fmaxf(ow, 0.f));
            float* op = out + (b * L + l_glob) * D + tn * 4;
            if (MODE == 2) {   // add h_local (already in d_out)
                float4 prev = ld4(op);
                r.x += prev.x; r.y += prev.y; r.z += prev.z; r.w += prev.w;
            }
            *reinterpret_cast<float4*>(op) = r;
        }
    }
}

// ---------------------------------------------------------------------------
extern "C" void kernel_launch(void* const* d_in, const int* in_sizes, int n_in,
                              void* d_out, int out_size, void* d_ws, size_t ws_size,
                              hipStream_t stream)
{
    const int*   inputs     = (const int*)d_in[0];
    const int*   adj        = (const int*)d_in[1];
    const int*   mask_item  = (const int*)d_in[2];
    const int*   item       = (const int*)d_in[3];
    const int*   adj_all    = (const int*)d_in[4];
    const float* num_weight = (const float*)d_in[5];
    const float* embedding  = (const float*)d_in[6];
    const float* a_local    = (const float*)d_in[7];
    const float* agg_w1     = (const float*)d_in[8];
    const float* agg_w2     = (const float*)d_in[9];
    const float* agg_w3     = (const float*)d_in[10];
    float* out = (float*)d_out;

    // workspace layout (all 16B-aligned): session | n1 | out0 | out1  (~43 MB)
    float* ws_session = (float*)d_ws;                        // 128*128 f32
    int*   ws_n1      = (int*)(ws_session + BATCH * D);      // 128*600 i32
    float* ws_out0    = (float*)(ws_n1 + BATCH * 600);       // 128*50*128 f32
    float* ws_out1    = ws_out0 + (size_t)BATCH * 50 * D;    // 128*600*128 f32

    local_agg_kernel<<<dim3(BATCH), 256, 0, stream>>>(inputs, adj, embedding, a_local, out);
    session_kernel<<<dim3(BATCH), 128, 0, stream>>>(item, mask_item, embedding, ws_session);
    n1_kernel<<<dim3(300), 256, 0, stream>>>(inputs, adj_all, ws_n1);

    // n_hop = 0
    global_kernel<0><<<dim3((50 + NL - 1) / NL, BATCH), 256, 0, stream>>>(
        inputs, adj_all, num_weight, embedding, ws_n1, ws_session,
        nullptr, nullptr, agg_w1, agg_w2, agg_w3, ws_out0, 50);
    global_kernel<1><<<dim3(600 / NL, BATCH), 256, 0, stream>>>(
        inputs, adj_all, num_weight, embedding, ws_n1, ws_session,
        nullptr, nullptr, agg_w1, agg_w2, agg_w3, ws_out1, 600);
    // n_hop = 1 (adds h_local already resident in d_out)
    global_kernel<2><<<dim3((50 + NL - 1) / NL, BATCH), 256, 0, stream>>>(
        inputs, adj_all, num_weight, embedding, ws_n1, ws_session,
        ws_out0, ws_out1, agg_w1 + 129 * D, agg_w2 + D, agg_w3 + 2 * D * D, out, 50);
}

// Round 2
// 355.517 us; speedup vs baseline: 3.4963x; 3.4963x over previous
//
#include <hip/hip_runtime.h>
#include <math.h>

#define BATCH 128
#define S 50
#define D 128
#define SAMPLE 12
#define NL 8

typedef __attribute__((ext_vector_type(8))) short short8v;
typedef __attribute__((ext_vector_type(4))) float f32x4;

__device__ __forceinline__ float leakyf(float x) { return x >= 0.f ? x : 0.2f * x; }
__device__ __forceinline__ unsigned short f2bf(float f) {
    union { float f; unsigned int u; } v; v.f = f;
    unsigned int u = v.u;
    return (unsigned short)((u + 0x7FFFu + ((u >> 16) & 1u)) >> 16);  // RNE
}
__device__ __forceinline__ float bf2f(unsigned short h) {
    union { float f; unsigned int u; } v; v.u = ((unsigned int)h) << 16; return v.f;
}

// ---------------------------------------------------------------------------
// h_local (unchanged fp32 path) -> d_out
// ---------------------------------------------------------------------------
__global__ __launch_bounds__(256) void local_agg_kernel(
    const int* __restrict__ inputs, const int* __restrict__ adj,
    const float* __restrict__ emb, const float* __restrict__ a_local,
    float* __restrict__ out)
{
    __shared__ float h[S][D];
    __shared__ float al[4][D];
    __shared__ float alpha[S][S];
    const int b = blockIdx.x;
    const int t = threadIdx.x;

    for (int idx = t; idx < S * D; idx += 256) {
        int i = idx / D, d = idx % D;
        h[i][d] = emb[inputs[b * S + i] * D + d];
    }
    for (int idx = t; idx < 4 * D; idx += 256) al[idx / D][idx % D] = a_local[idx];
    __syncthreads();

    for (int p = t; p < S * S; p += 256) {
        int i = p / S, j = p % S;
        int a = adj[b * S * S + p];
        float v = -9e15f;
        if (a >= 1 && a <= 4) {
            const float* ak = al[a - 1];
            float dot = 0.f;
            #pragma unroll 4
            for (int d = 0; d < D; ++d) dot += h[i][d] * h[j][d] * ak[d];
            v = leakyf(dot);
        }
        alpha[i][j] = v;
    }
    __syncthreads();

    if (t < S) {
        float m = -INFINITY;
        for (int j = 0; j < S; ++j) m = fmaxf(m, alpha[t][j]);
        float ssum = 0.f;
        for (int j = 0; j < S; ++j) { float e = expf(alpha[t][j] - m); alpha[t][j] = e; ssum += e; }
        float inv = 1.f / ssum;
        for (int j = 0; j < S; ++j) alpha[t][j] *= inv;
    }
    __syncthreads();

    for (int idx = t; idx < S * D; idx += 256) {
        int i = idx / D, d = idx % D;
        float acc = 0.f;
        #pragma unroll 5
        for (int j = 0; j < S; ++j) acc += alpha[i][j] * h[j][d];
        out[b * S * D + idx] = acc;
    }
}

__global__ __launch_bounds__(128) void session_kernel(
    const int* __restrict__ item, const int* __restrict__ mask,
    const float* __restrict__ emb, float* __restrict__ session)
{
    const int b = blockIdx.x, d = threadIdx.x;
    float num = 0.f, den = 0.f;
    for (int s = 0; s < S; ++s) {
        float m = (float)mask[b * S + s];
        num += m * emb[item[b * S + s] * D + d];
        den += m;
    }
    session[b * D + d] = num / den;
}

__global__ __launch_bounds__(256) void n1_kernel(
    const int* __restrict__ inputs, const int* __restrict__ adj_all,
    int* __restrict__ n1)
{
    int idx = blockIdx.x * 256 + threadIdx.x;
    if (idx >= BATCH * 600) return;
    int b = idx / 600, j = idx % 600;
    int node = inputs[b * S + j / SAMPLE];
    n1[idx] = adj_all[node * SAMPLE + j % SAMPLE];
}

// ---------------------------------------------------------------------------
// prep: W1T bf16 [hop][n(128)][k(128)], W3T bf16 [hop][n(128)][k(256)]
// ---------------------------------------------------------------------------
__global__ __launch_bounds__(256) void prep_kernel(
    const float* __restrict__ w1, const float* __restrict__ w3,
    unsigned short* __restrict__ w1t, unsigned short* __restrict__ w3t)
{
    int idx = blockIdx.x * 256 + threadIdx.x;
    if (idx < 2 * 128 * 128) {
        int h = idx >> 14, r = idx & 16383, n = r >> 7, k = r & 127;
        w1t[idx] = f2bf(w1[h * 129 * 128 + k * 128 + n]);
    } else {
        int j = idx - 2 * 128 * 128;
        int h = j >> 15, r = j & 32767, n = r >> 8, k = r & 255;
        w3t[j] = f2bf(w3[h * 256 * 128 + k * 128 + n]);
    }
}

// ---------------------------------------------------------------------------
// Fused _global_agg with bf16 MFMA.
// MODE 0: self=E[inputs], neigh=E[n1]            -> out0 (bf16)
// MODE 1: self=E[n1],     neigh=E[adj_all[n1]]   -> out1 (bf16)
// MODE 2: self=out0,      neigh=out1, + h_local  -> d_out (f32)
// ---------------------------------------------------------------------------
template <int MODE>
__global__ __launch_bounds__(256, 2) void global_kernel(
    const int* __restrict__ inputs, const int* __restrict__ adj_all,
    const float* __restrict__ num_weight, const float* __restrict__ emb,
    const int* __restrict__ n1, const float* __restrict__ session,
    const unsigned short* __restrict__ ent_self, const unsigned short* __restrict__ ent_neigh,
    const unsigned short* __restrict__ w1t, const float* __restrict__ w1,
    const float* __restrict__ w2, const unsigned short* __restrict__ w3t,
    unsigned short* __restrict__ outb, float* __restrict__ outf, int L)
{
    __shared__ unsigned short nvL[96 * 128];  // bf16, XOR-swizzled, rows = l*12+s
    __shared__ unsigned short A2[16 * 256];   // bf16, XOR-swizzled, [self | neigh]
    __shared__ float score_w[4][96];
    __shared__ float score[96];
    __shared__ float sessL[128];
    __shared__ float w1lastL[128];
    __shared__ float nwgtL[96];
    __shared__ int   selfNode[8];
    __shared__ int   neighIdx[96];

    const int b = blockIdx.y;
    const int l0 = blockIdx.x * NL;
    const int t = threadIdx.x;
    const int lane = t & 63;
    const int wv = t >> 6;          // wave id 0..3
    const int cn = lane & 15;       // col-within-tile / A-row-within-tile
    const int cg = lane >> 4;       // k-group

    if (t < 128) sessL[t] = session[b * 128 + t];
    else         w1lastL[t - 128] = w1[128 * 128 + (t - 128)];
    if (t < 8) {
        int l = l0 + t;
        selfNode[t] = (l < L) ? ((MODE == 1) ? n1[b * 600 + l] : inputs[b * S + l]) : -1;
    }
    __syncthreads();

    if (t < 96) {
        int li = t / SAMPLE, s2 = t % SAMPLE;
        int node = selfNode[li];
        int row = -1; float wgt = 0.f;
        if (node >= 0) {
            if (MODE == 0)      row = n1[b * 600 + (l0 + li) * SAMPLE + s2];
            else if (MODE == 1) row = adj_all[node * SAMPLE + s2];
            else                row = b * 600 + (l0 + li) * SAMPLE + s2;
            wgt = num_weight[node * SAMPLE + s2];
        }
        neighIdx[t] = row; nwgtL[t] = wgt;
    }
    // zero A2 rows 8..15 (padding rows of the M=16 GEMM2 tile)
    reinterpret_cast<float4*>((char*)A2 + 8 * 512)[t] = make_float4(0.f, 0.f, 0.f, 0.f);
    __syncthreads();

    // ---- stage neighbor rows -> nvL (bf16, swizzled) ----
    for (int q = t; q < 96 * 32; q += 256) {
        int m = q >> 5, dq = q & 31;
        int row = neighIdx[m];
        ushort4 bv = make_ushort4(0, 0, 0, 0);
        if (row >= 0) {
            if (MODE == 2) {
                bv = reinterpret_cast<const ushort4*>(ent_neigh)[row * 32 + dq];
            } else {
                float4 v = reinterpret_cast<const float4*>(emb)[row * 32 + dq];
                bv.x = f2bf(v.x); bv.y = f2bf(v.y); bv.z = f2bf(v.z); bv.w = f2bf(v.w);
            }
        }
        unsigned byteoff = m * 256 + ((dq * 8) ^ ((m & 7) << 4));
        *reinterpret_cast<ushort4*>((char*)nvL + byteoff) = bv;
    }
    // ---- stage self rows -> A2 k=[0,128) ----
    {
        int li = t >> 5, dq = t & 31;
        int l = l0 + li;
        ushort4 bv = make_ushort4(0, 0, 0, 0);
        if (l < L) {
            if (MODE == 2) {
                bv = reinterpret_cast<const ushort4*>(ent_self)[(b * 50 + l) * 32 + dq];
            } else {
                float4 v = reinterpret_cast<const float4*>(emb)[selfNode[li] * 32 + dq];
                bv.x = f2bf(v.x); bv.y = f2bf(v.y); bv.z = f2bf(v.z); bv.w = f2bf(v.w);
            }
        }
        unsigned byteoff = li * 512 + ((dq * 8) ^ ((li & 7) << 4));
        *reinterpret_cast<ushort4*>((char*)A2 + byteoff) = bv;
    }
    __syncthreads();

    // ---- GEMM1: z[96,128] = nv @ (sess (.) W1[:128,:]) ----
    f32x4 acc[6][2];
    #pragma unroll
    for (int mt = 0; mt < 6; ++mt)
        #pragma unroll
        for (int j = 0; j < 2; ++j)
            acc[mt][j] = (f32x4){0.f, 0.f, 0.f, 0.f};

    #pragma unroll
    for (int kk = 0; kk < 4; ++kk) {
        int kbase = kk * 32 + cg * 8;
        short8v bfr[2];
        #pragma unroll
        for (int j = 0; j < 2; ++j) {
            int n = (2 * wv + j) * 16 + cn;
            short8v braw = *reinterpret_cast<const short8v*>(w1t + n * 128 + kbase);
            short8v bs;
            #pragma unroll
            for (int e = 0; e < 8; ++e) {
                float f = bf2f((unsigned short)braw[e]) * sessL[kbase + e];
                bs[e] = (short)f2bf(f);
            }
            bfr[j] = bs;
        }
        #pragma unroll
        for (int mt = 0; mt < 6; ++mt) {
            unsigned byteoff = (mt * 16 + cn) * 256 + ((kbase * 2) ^ ((cn & 7) << 4));
            short8v a = *reinterpret_cast<const short8v*>((const char*)nvL + byteoff);
            acc[mt][0] = __builtin_amdgcn_mfma_f32_16x16x32_bf16(a, bfr[0], acc[mt][0], 0, 0, 0);
            acc[mt][1] = __builtin_amdgcn_mfma_f32_16x16x32_bf16(a, bfr[1], acc[mt][1], 0, 0, 0);
        }
    }

    // ---- epilogue: K=129 rank-1 term + leaky + @W2 -> per-wave partial scores
    {
        float w2v0 = w2[(2 * wv) * 16 + cn];
        float w2v1 = w2[(2 * wv + 1) * 16 + cn];
        float w1l0 = w1lastL[(2 * wv) * 16 + cn];
        float w1l1 = w1lastL[(2 * wv + 1) * 16 + cn];
        #pragma unroll
        for (int mt = 0; mt < 6; ++mt) {
            #pragma unroll
            for (int r = 0; r < 4; ++r) {
                float nw = nwgtL[mt * 16 + cg * 4 + r];
                float z0 = acc[mt][0][r] + nw * w1l0;
                float z1 = acc[mt][1][r] + nw * w1l1;
                float v = leakyf(z0) * w2v0 + leakyf(z1) * w2v1;
                v += __shfl_xor(v, 1); v += __shfl_xor(v, 2);
                v += __shfl_xor(v, 4); v += __shfl_xor(v, 8);
                if (cn == 0) score_w[wv][mt * 16 + cg * 4 + r] = v;
            }
        }
    }
    __syncthreads();

    // ---- softmax over 12 samples per l ----
    if (t < 8) {
        float e[SAMPLE]; float mx = -INFINITY;
        #pragma unroll
        for (int s2 = 0; s2 < SAMPLE; ++s2) {
            int m = t * SAMPLE + s2;
            float v = score_w[0][m] + score_w[1][m] + score_w[2][m] + score_w[3][m];
            e[s2] = v; mx = fmaxf(mx, v);
        }
        float ssum = 0.f;
        #pragma unroll
        for (int s2 = 0; s2 < SAMPLE; ++s2) { e[s2] = expf(e[s2] - mx); ssum += e[s2]; }
        float inv = 1.f / ssum;
        #pragma unroll
        for (int s2 = 0; s2 < SAMPLE; ++s2) score[t * SAMPLE + s2] = e[s2] * inv;
    }
    __syncthreads();

    // ---- phase 4: neigh[l][d] = sum_s alpha*nv -> A2 k=[128,256) ----
    #pragma unroll
    for (int i = 0; i < 4; ++i) {
        int idx = i * 256 + t;
        int l = idx >> 7, d = idx & 127;
        float a = 0.f;
        #pragma unroll
        for (int s2 = 0; s2 < SAMPLE; ++s2) {
            int m = l * SAMPLE + s2;
            unsigned byteoff = m * 256 + ((2 * d) ^ ((m & 7) << 4));
            a += score[m] * bf2f(*reinterpret_cast<const unsigned short*>((const char*)nvL + byteoff));
        }
        unsigned ob = l * 512 + ((2 * (128 + d)) ^ ((l & 7) << 4));
        *reinterpret_cast<unsigned short*>((char*)A2 + ob) = f2bf(a);
    }
    __syncthreads();

    // ---- GEMM2: out[16,128] = A2[16,256] @ W3 ----
    f32x4 acc2[2];
    acc2[0] = (f32x4){0.f, 0.f, 0.f, 0.f};
    acc2[1] = (f32x4){0.f, 0.f, 0.f, 0.f};
    #pragma unroll
    for (int kk = 0; kk < 8; ++kk) {
        int kbase = kk * 32 + cg * 8;
        unsigned ab = cn * 512 + ((kbase * 2) ^ ((cn & 7) << 4));
        short8v a = *reinterpret_cast<const short8v*>((const char*)A2 + ab);
        #pragma unroll
        for (int j = 0; j < 2; ++j) {
            int n = (2 * wv + j) * 16 + cn;
            short8v bb = *reinterpret_cast<const short8v*>(w3t + n * 256 + kbase);
            acc2[j] = __builtin_amdgcn_mfma_f32_16x16x32_bf16(a, bb, acc2[j], 0, 0, 0);
        }
    }
    // ---- relu + store ----
    #pragma unroll
    for (int j = 0; j < 2; ++j) {
        int n = (2 * wv + j) * 16 + cn;
        #pragma unroll
        for (int r = 0; r < 4; ++r) {
            int rowi = cg * 4 + r;
            if (rowi < 8 && (l0 + rowi) < L) {
                float val = fmaxf(acc2[j][r], 0.f);
                if (MODE == 2) {
                    float* p = outf + ((size_t)(b * 50) + l0 + rowi) * 128 + n;
                    *p = val + *p;                 // add h_local already in d_out
                } else {
                    outb[((size_t)b * L + l0 + rowi) * 128 + n] = f2bf(val);
                }
            }
        }
    }
}

// ---------------------------------------------------------------------------
extern "C" void kernel_launch(void* const* d_in, const int* in_sizes, int n_in,
                              void* d_out, int out_size, void* d_ws, size_t ws_size,
                              hipStream_t stream)
{
    const int*   inputs     = (const int*)d_in[0];
    const int*   adj        = (const int*)d_in[1];
    const int*   mask_item  = (const int*)d_in[2];
    const int*   item       = (const int*)d_in[3];
    const int*   adj_all    = (const int*)d_in[4];
    const float* num_weight = (const float*)d_in[5];
    const float* embedding  = (const float*)d_in[6];
    const float* a_local    = (const float*)d_in[7];
    const float* agg_w1     = (const float*)d_in[8];
    const float* agg_w2     = (const float*)d_in[9];
    const float* agg_w3     = (const float*)d_in[10];
    float* out = (float*)d_out;

    // workspace layout (16B aligned): session | n1 | w1t | w3t | out0 | out1
    float*          ws_session = (float*)d_ws;                             // 16384 f32
    int*            ws_n1      = (int*)(ws_session + 16384);               // 76800 i32
    unsigned short* ws_w1t     = (unsigned short*)(ws_n1 + 76800);         // 2*128*128
    unsigned short* ws_w3t     = ws_w1t + 2 * 128 * 128;                   // 2*128*256
    unsigned short* ws_out0    = ws_w3t + 2 * 128 * 256;                   // 128*50*128
    unsigned short* ws_out1    = ws_out0 + (size_t)BATCH * 50 * D;         // 128*600*128

    prep_kernel<<<dim3(384), 256, 0, stream>>>(agg_w1, agg_w3, ws_w1t, ws_w3t);
    local_agg_kernel<<<dim3(BATCH), 256, 0, stream>>>(inputs, adj, embedding, a_local, out);
    session_kernel<<<dim3(BATCH), 128, 0, stream>>>(item, mask_item, embedding, ws_session);
    n1_kernel<<<dim3(300), 256, 0, stream>>>(inputs, adj_all, ws_n1);

    // n_hop = 0 (weights hop index 0)
    global_kernel<0><<<dim3(7, BATCH), 256, 0, stream>>>(
        inputs, adj_all, num_weight, embedding, ws_n1, ws_session,
        nullptr, nullptr, ws_w1t, agg_w1, agg_w2, ws_w3t, ws_out0, nullptr, 50);
    global_kernel<1><<<dim3(75, BATCH), 256, 0, stream>>>(
        inputs, adj_all, num_weight, embedding, ws_n1, ws_session,
        nullptr, nullptr, ws_w1t, agg_w1, agg_w2, ws_w3t, ws_out1, nullptr, 600);
    // n_hop = 1 (weights hop index 1), adds h_local already resident in d_out
    global_kernel<2><<<dim3(7, BATCH), 256, 0, stream>>>(
        inputs, adj_all, num_weight, embedding, ws_n1, ws_session,
        ws_out0, ws_out1, ws_w1t + 128 * 128, agg_w1 + 129 * 128,
        agg_w2 + 128, ws_w3t + 128 * 256, nullptr, out, 50);
}

// Round 3
// 330.362 us; speedup vs baseline: 3.7625x; 1.0761x over previous
//
#include <hip/hip_runtime.h>
#include <math.h>

#define BATCH 128
#define S 50
#define D 128
#define SAMPLE 12

typedef __attribute__((ext_vector_type(8))) short short8v;
typedef __attribute__((ext_vector_type(4))) float f32x4;
typedef unsigned short u16;

__device__ __forceinline__ float leakyf(float x) { return x >= 0.f ? x : 0.2f * x; }
__device__ __forceinline__ u16 f2bf(float f) {
    union { float f; unsigned u; } v; v.f = f;
    unsigned u = v.u;
    return (u16)((u + 0x7FFFu + ((u >> 16) & 1u)) >> 16);  // RNE
}
__device__ __forceinline__ float bf2f(u16 h) {
    union { float f; unsigned u; } v; v.u = ((unsigned)h) << 16; return v.f;
}

// ---------------------------------------------------------------------------
// setup: session vector + 1-hop neighbor index table
// ---------------------------------------------------------------------------
__global__ __launch_bounds__(256) void setup_kernel(
    const int* __restrict__ item, const int* __restrict__ mask,
    const int* __restrict__ inputs, const int* __restrict__ adj_all,
    const float* __restrict__ emb, float* __restrict__ session, int* __restrict__ n1)
{
    const int bx = blockIdx.x, t = threadIdx.x;
    if (bx < BATCH) {
        if (t < 128) {
            float num = 0.f, den = 0.f;
            for (int s = 0; s < S; ++s) {
                float m = (float)mask[bx * S + s];
                num += m * emb[item[bx * S + s] * D + t];
                den += m;
            }
            session[bx * D + t] = num / den;
        }
    } else {
        int idx = (bx - BATCH) * 256 + t;
        if (idx < BATCH * 600) {
            int b = idx / 600, j = idx % 600;
            n1[idx] = adj_all[inputs[b * S + j / SAMPLE] * SAMPLE + j % SAMPLE];
        }
    }
}

// ---------------------------------------------------------------------------
// prep: emb->bf16 (10.2MB), sessW1[hop][b][n][k] bf16 (8MB), W3T bf16
// ---------------------------------------------------------------------------
__global__ __launch_bounds__(256) void prep_kernel(
    const float* __restrict__ emb, const float* __restrict__ w1,
    const float* __restrict__ w3, const float* __restrict__ session,
    u16* __restrict__ emb_bf, u16* __restrict__ sw1, u16* __restrict__ w3t)
{
    const int bx = blockIdx.x, t = threadIdx.x;
    if (bx < 2500) {                       // embedding -> bf16, 8 elems/thread
        int idx = bx * 256 + t;
        const float4* src = reinterpret_cast<const float4*>(emb) + (size_t)idx * 2;
        float4 a = src[0], c = src[1];
        u16 o[8] = {f2bf(a.x), f2bf(a.y), f2bf(a.z), f2bf(a.w),
                    f2bf(c.x), f2bf(c.y), f2bf(c.z), f2bf(c.w)};
        *reinterpret_cast<uint4*>(emb_bf + (size_t)idx * 8) = *reinterpret_cast<uint4*>(o);
    } else if (bx < 2756) {                // sessW1: block = (hop,b)
        int id = bx - 2500, hop = id >> 7, b = id & 127;
        const float* w1s = w1 + hop * 129 * 128;
        const float* se = session + b * 128;
        int n = t >> 1, kh = (t & 1) * 64;
        u16* dst = sw1 + (((size_t)(hop * 128 + b) * 128 + n) * 128) + kh;
        for (int kq = 0; kq < 64; kq += 8) {
            u16 o[8];
            #pragma unroll
            for (int e = 0; e < 8; ++e) { int k = kh + kq + e; o[e] = f2bf(w1s[k * 128 + n] * se[k]); }
            *reinterpret_cast<uint4*>(dst + kq) = *reinterpret_cast<uint4*>(o);
        }
    } else {                               // W3T
        int j = (bx - 2756) * 256 + t;     // < 8192, 8 elems/thread
        int hop = j >> 12, r = j & 4095, n = r >> 5, k0 = (r & 31) * 8;
        const float* w3s = w3 + hop * 256 * 128;
        u16 o[8];
        #pragma unroll
        for (int e = 0; e < 8; ++e) o[e] = f2bf(w3s[(k0 + e) * 128 + n]);
        *reinterpret_cast<uint4*>(w3t + ((size_t)hop * 128 + n) * 256 + k0) = *reinterpret_cast<uint4*>(o);
    }
}

// ---------------------------------------------------------------------------
// Fused main kernel.
// PATH 0, grid (83,128): bx<75 -> mode1 (L=600, out1); bx 75..81 -> mode0
//                        (L=50, out0); bx==82 -> local_agg (writes d_out).
// PATH 2, grid (7,128):  mode2 (self=out0, neigh=out1, hop1 wts, += d_out).
// ---------------------------------------------------------------------------
template <int PATH>
__global__ __launch_bounds__(256, 4) void main_kernel(
    const int* __restrict__ inputs, const int* __restrict__ adj,
    const int* __restrict__ adj_all, const float* __restrict__ num_weight,
    const float* __restrict__ emb, const float* __restrict__ a_local,
    const int* __restrict__ n1,
    const u16* __restrict__ emb_bf, const u16* __restrict__ sw1,
    const float* __restrict__ w1, const float* __restrict__ w2,
    const u16* __restrict__ w3t,
    const u16* __restrict__ in0, const u16* __restrict__ in1,
    u16* __restrict__ o0, u16* __restrict__ o1, float* __restrict__ outf)
{
    __shared__ __align__(16) char smem[37664];
    const int b = blockIdx.y;
    const int t = threadIdx.x;
    const int bx = blockIdx.x;

    if (PATH == 0 && bx == 82) {
        // ------------------- local aggregation -------------------
        float (*h)[D]     = (float(*)[D])smem;            // 25600 B
        float (*al)[D]    = (float(*)[D])(smem + 25600);  // 2048 B
        float (*alpha)[S] = (float(*)[S])(smem + 27648);  // 10000 B

        for (int idx = t; idx < S * D; idx += 256) {
            int i = idx / D, d = idx % D;
            h[i][d] = emb[inputs[b * S + i] * D + d];
        }
        for (int idx = t; idx < 4 * D; idx += 256) al[idx / D][idx % D] = a_local[idx];
        __syncthreads();

        for (int p = t; p < S * S; p += 256) {
            int i = p / S, j = p % S;
            int a = adj[b * S * S + p];
            float v = -9e15f;
            if (a >= 1 && a <= 4) {
                const float* ak = al[a - 1];
                float dot = 0.f;
                #pragma unroll 4
                for (int d = 0; d < D; ++d) dot += h[i][d] * h[j][d] * ak[d];
                v = leakyf(dot);
            }
            alpha[i][j] = v;
        }
        __syncthreads();

        if (t < S) {
            float m = -INFINITY;
            for (int j = 0; j < S; ++j) m = fmaxf(m, alpha[t][j]);
            float ssum = 0.f;
            for (int j = 0; j < S; ++j) { float e = expf(alpha[t][j] - m); alpha[t][j] = e; ssum += e; }
            float inv = 1.f / ssum;
            for (int j = 0; j < S; ++j) alpha[t][j] *= inv;
        }
        __syncthreads();

        for (int idx = t; idx < S * D; idx += 256) {
            int i = idx / D, d = idx % D;
            float acc = 0.f;
            #pragma unroll 5
            for (int j = 0; j < S; ++j) acc += alpha[i][j] * h[j][d];
            outf[b * S * D + idx] = acc;
        }
        return;
    }

    // ------------------- global aggregation -------------------
    int mode, l0, L, hop;
    const u16 *nsrc, *ssrc;
    u16* outb;
    if (PATH == 2)      { mode = 2; l0 = bx * 8;        L = 50;  nsrc = in1;    ssrc = in0;    outb = nullptr; hop = 1; }
    else if (bx < 75)   { mode = 1; l0 = bx * 8;        L = 600; nsrc = emb_bf; ssrc = emb_bf; outb = o1;      hop = 0; }
    else                { mode = 0; l0 = (bx - 75) * 8; L = 50;  nsrc = emb_bf; ssrc = emb_bf; outb = o0;      hop = 0; }

    u16* nvL = (u16*)smem;                               // 96*128 bf16, swizzled
    u16* A2  = (u16*)(smem + 24576);                     // 16*256 bf16, swizzled
    float (*score_w)[96] = (float(*)[96])(smem + 32768); // 4 x 96
    float* score    = (float*)(smem + 34304);            // 96
    float* nwgt     = (float*)(smem + 34688);            // 96
    int*   neighIdx = (int*)(smem + 35072);              // 96
    int*   selfNode = (int*)(smem + 35456);              // 8

    const u16*   sw1b   = sw1 + (size_t)(hop * 128 + b) * 16384;
    const float* w1last = w1 + hop * 129 * 128 + 128 * 128;
    const float* w2h    = w2 + hop * 128;
    const u16*   w3th   = w3t + hop * 32768;

    const int lane = t & 63, wv = t >> 6, cn = lane & 15, cg = lane >> 4;

    if (t < 8) {
        int l = l0 + t;
        selfNode[t] = (l < L) ? ((mode == 1) ? n1[b * 600 + l] : inputs[b * S + l]) : -1;
    }
    __syncthreads();

    if (t < 96) {
        int li = t / SAMPLE, s2 = t % SAMPLE;
        int node = selfNode[li];
        int row = -1; float wgt = 0.f;
        if (node >= 0) {
            if (mode == 0)      row = n1[b * 600 + (l0 + li) * SAMPLE + s2];
            else if (mode == 1) row = adj_all[node * SAMPLE + s2];
            else                row = b * 600 + (l0 + li) * SAMPLE + s2;
            wgt = num_weight[node * SAMPLE + s2];
        }
        neighIdx[t] = row; nwgt[t] = wgt;
    }
    // zero A2 rows 8..15 (padding rows of GEMM2's M=16 tile)
    *reinterpret_cast<uint4*>((char*)A2 + 8 * 512 + t * 16) = make_uint4(0, 0, 0, 0);
    __syncthreads();

    // ---- stage neighbor rows (bf16, swizzled), 6 x 16B per thread ----
    #pragma unroll
    for (int i = 0; i < 6; ++i) {
        int q = i * 256 + t;            // 96 rows x 16 chunks
        int m = q >> 4, dq = q & 15;
        int row = neighIdx[m];
        uint4 v = make_uint4(0, 0, 0, 0);
        if (row >= 0) v = *reinterpret_cast<const uint4*>(nsrc + (size_t)row * 128 + dq * 8);
        *reinterpret_cast<uint4*>((char*)nvL + m * 256 + ((dq * 16) ^ ((m & 7) << 4))) = v;
    }
    // ---- stage self rows -> A2 k=[0,128) ----
    if (t < 128) {
        int li = t >> 4, dq = t & 15;
        int l = l0 + li;
        uint4 v = make_uint4(0, 0, 0, 0);
        if (l < L) {
            int srow = (mode == 2) ? (b * 50 + l) : selfNode[li];
            v = *reinterpret_cast<const uint4*>(ssrc + (size_t)srow * 128 + dq * 8);
        }
        *reinterpret_cast<uint4*>((char*)A2 + li * 512 + ((dq * 16) ^ ((li & 7) << 4))) = v;
    }
    __syncthreads();

    // ---- GEMM1: z[96,128] = nv @ sessW1b  (B direct from L2, no repack) ----
    f32x4 acc[6][2];
    #pragma unroll
    for (int mt = 0; mt < 6; ++mt) {
        acc[mt][0] = (f32x4){0.f, 0.f, 0.f, 0.f};
        acc[mt][1] = (f32x4){0.f, 0.f, 0.f, 0.f};
    }
    #pragma unroll
    for (int kk = 0; kk < 4; ++kk) {
        int kbase = kk * 32 + cg * 8;
        short8v b0 = *reinterpret_cast<const short8v*>(sw1b + ((2 * wv) * 16 + cn) * 128 + kbase);
        short8v b1 = *reinterpret_cast<const short8v*>(sw1b + ((2 * wv + 1) * 16 + cn) * 128 + kbase);
        #pragma unroll
        for (int mt = 0; mt < 6; ++mt) {
            short8v a = *reinterpret_cast<const short8v*>(
                (const char*)nvL + (mt * 16 + cn) * 256 + ((kbase * 2) ^ ((cn & 7) << 4)));
            acc[mt][0] = __builtin_amdgcn_mfma_f32_16x16x32_bf16(a, b0, acc[mt][0], 0, 0, 0);
            acc[mt][1] = __builtin_amdgcn_mfma_f32_16x16x32_bf16(a, b1, acc[mt][1], 0, 0, 0);
        }
    }

    // ---- epilogue: K=129 rank-1 term + leaky + @W2 -> per-wave partials ----
    {
        float w2v0 = w2h[(2 * wv) * 16 + cn];
        float w2v1 = w2h[(2 * wv + 1) * 16 + cn];
        float w1l0 = w1last[(2 * wv) * 16 + cn];
        float w1l1 = w1last[(2 * wv + 1) * 16 + cn];
        #pragma unroll
        for (int mt = 0; mt < 6; ++mt) {
            #pragma unroll
            for (int r = 0; r < 4; ++r) {
                float nw = nwgt[mt * 16 + cg * 4 + r];
                float v = leakyf(acc[mt][0][r] + nw * w1l0) * w2v0 +
                          leakyf(acc[mt][1][r] + nw * w1l1) * w2v1;
                v += __shfl_xor(v, 1); v += __shfl_xor(v, 2);
                v += __shfl_xor(v, 4); v += __shfl_xor(v, 8);
                if (cn == 0) score_w[wv][mt * 16 + cg * 4 + r] = v;
            }
        }
    }
    __syncthreads();

    // ---- softmax over 12 samples per l ----
    if (t < 8) {
        float e[SAMPLE]; float mx = -INFINITY;
        #pragma unroll
        for (int s2 = 0; s2 < SAMPLE; ++s2) {
            int m = t * SAMPLE + s2;
            float v = score_w[0][m] + score_w[1][m] + score_w[2][m] + score_w[3][m];
            e[s2] = v; mx = fmaxf(mx, v);
        }
        float ssum = 0.f;
        #pragma unroll
        for (int s2 = 0; s2 < SAMPLE; ++s2) { e[s2] = expf(e[s2] - mx); ssum += e[s2]; }
        float inv = 1.f / ssum;
        #pragma unroll
        for (int s2 = 0; s2 < SAMPLE; ++s2) score[t * SAMPLE + s2] = e[s2] * inv;
    }
    __syncthreads();

    // ---- phase 4: neigh[l][d] = sum_s alpha*nv -> A2 k=[128,256), packed ----
    #pragma unroll
    for (int i = 0; i < 2; ++i) {
        int idx = i * 256 + t;          // 8 l x 64 d-pairs
        int l = idx >> 6, d2 = idx & 63;
        float a0 = 0.f, a1 = 0.f;
        #pragma unroll
        for (int s2 = 0; s2 < SAMPLE; ++s2) {
            int m = l * SAMPLE + s2;
            unsigned pk = *reinterpret_cast<const unsigned*>(
                (const char*)nvL + m * 256 + ((4 * d2) ^ ((m & 7) << 4)));
            float sc = score[m];
            a0 += sc * bf2f((u16)(pk & 0xffff));
            a1 += sc * bf2f((u16)(pk >> 16));
        }
        unsigned packed = ((unsigned)f2bf(a1) << 16) | f2bf(a0);
        *reinterpret_cast<unsigned*>((char*)A2 + l * 512 + ((256 + 4 * d2) ^ ((l & 7) << 4))) = packed;
    }
    __syncthreads();

    // ---- GEMM2: out[16,128] = A2[16,256] @ W3T ----
    f32x4 acc2[2];
    acc2[0] = (f32x4){0.f, 0.f, 0.f, 0.f};
    acc2[1] = (f32x4){0.f, 0.f, 0.f, 0.f};
    #pragma unroll
    for (int kk = 0; kk < 8; ++kk) {
        int kbase = kk * 32 + cg * 8;
        short8v a = *reinterpret_cast<const short8v*>(
            (const char*)A2 + cn * 512 + ((kbase * 2) ^ ((cn & 7) << 4)));
        short8v bb0 = *reinterpret_cast<const short8v*>(w3th + ((2 * wv) * 16 + cn) * 256 + kbase);
        short8v bb1 = *reinterpret_cast<const short8v*>(w3th + ((2 * wv + 1) * 16 + cn) * 256 + kbase);
        acc2[0] = __builtin_amdgcn_mfma_f32_16x16x32_bf16(a, bb0, acc2[0], 0, 0, 0);
        acc2[1] = __builtin_amdgcn_mfma_f32_16x16x32_bf16(a, bb1, acc2[1], 0, 0, 0);
    }
    // ---- relu + store ----
    #pragma unroll
    for (int j = 0; j < 2; ++j) {
        int n = (2 * wv + j) * 16 + cn;
        #pragma unroll
        for (int r = 0; r < 4; ++r) {
            int rowi = cg * 4 + r;
            if (rowi < 8 && (l0 + rowi) < L) {
                float val = fmaxf(acc2[j][r], 0.f);
                if (PATH == 2) {
                    float* p = outf + ((size_t)(b * 50) + l0 + rowi) * 128 + n;
                    *p = val + *p;      // += h_local already in d_out
                } else {
                    outb[((size_t)b * L + l0 + rowi) * 128 + n] = f2bf(val);
                }
            }
        }
    }
}

// ---------------------------------------------------------------------------
extern "C" void kernel_launch(void* const* d_in, const int* in_sizes, int n_in,
                              void* d_out, int out_size, void* d_ws, size_t ws_size,
                              hipStream_t stream)
{
    const int*   inputs     = (const int*)d_in[0];
    const int*   adj        = (const int*)d_in[1];
    const int*   mask_item  = (const int*)d_in[2];
    const int*   item       = (const int*)d_in[3];
    const int*   adj_all    = (const int*)d_in[4];
    const float* num_weight = (const float*)d_in[5];
    const float* embedding  = (const float*)d_in[6];
    const float* a_local    = (const float*)d_in[7];
    const float* agg_w1     = (const float*)d_in[8];
    const float* agg_w2     = (const float*)d_in[9];
    const float* agg_w3     = (const float*)d_in[10];
    float* out = (float*)d_out;

    // workspace layout (16B aligned)
    char* w = (char*)d_ws;
    float* ws_session = (float*)(w);                    //     65,536 B
    int*   ws_n1      = (int*)(w + 65536);              //    307,200 B
    u16*   ws_emb     = (u16*)(w + 372736);             // 10,240,000 B
    u16*   ws_sw1     = (u16*)(w + 10612736);           //  8,388,608 B
    u16*   ws_w3t     = (u16*)(w + 19001344);           //    131,072 B
    u16*   ws_out0    = (u16*)(w + 19132416);           //  1,638,400 B
    u16*   ws_out1    = (u16*)(w + 20770816);           // 19,660,800 B (end ~40.4 MB)

    setup_kernel<<<dim3(BATCH + 300), 256, 0, stream>>>(
        item, mask_item, inputs, adj_all, embedding, ws_session, ws_n1);
    prep_kernel<<<dim3(2788), 256, 0, stream>>>(
        embedding, agg_w1, agg_w3, ws_session, ws_emb, ws_sw1, ws_w3t);

    // fused: mode1 (75) + mode0 (7) + local_agg (1) per batch
    main_kernel<0><<<dim3(83, BATCH), 256, 0, stream>>>(
        inputs, adj, adj_all, num_weight, embedding, a_local, ws_n1,
        ws_emb, ws_sw1, agg_w1, agg_w2, ws_w3t,
        nullptr, nullptr, ws_out0, ws_out1, out);

    // mode2: hop-1 weights, self=out0, neigh=out1, += h_local in d_out
    main_kernel<2><<<dim3(7, BATCH), 256, 0, stream>>>(
        inputs, adj, adj_all, num_weight, embedding, a_local, ws_n1,
        ws_emb, ws_sw1, agg_w1, agg_w2, ws_w3t,
        ws_out0, ws_out1, nullptr, nullptr, out);
}